// Round 1
// baseline (67.789 us; speedup 1.0000x reference)
//
#include <hip/hip_runtime.h>

// Problem constants (from reference)
constexpr int Bn    = 262144;
constexpr int NNUM  = 64;
constexpr int FCAT  = 32;
constexpr int NCAT  = 8;
constexpr int NFEAT = NNUM + FCAT * NCAT;  // 320
constexpr int NPHEN = NNUM + FCAT;         // 96

// tanh(x) given a = 2x:  tanh(x) = 1 - 2/(exp(2x)+1)
// exp(inf)->inf -> rcp->0 -> +1 ;  exp(-inf)->0 -> rcp(1)=1 -> -1  (saturates correctly)
__device__ __forceinline__ float tanh_from_2x(float a) {
    float e = __expf(a);                        // v_mul + v_exp_f32
    float r = __builtin_amdgcn_rcpf(e + 1.0f);  // v_rcp_f32
    return fmaf(-2.0f, r, 1.0f);
}

__global__ __launch_bounds__(256) void model_kernel(
    const float* __restrict__ num_x,   // (B, 64)
    const float* __restrict__ cat_x,   // (32, B, 8)
    const float* __restrict__ W,       // (2, 320)
    const float* __restrict__ M,       // (2, 96)
    float* __restrict__ out)           // (2, B)
{
    // Stage weights in LDS; store 2*W so the dot product is directly exp()'s arg.
    __shared__ float sW2[2 * NFEAT];
    __shared__ float sM[2 * NPHEN];
    const int tid = threadIdx.x;
    for (int i = tid; i < 2 * NFEAT; i += 256) sW2[i] = 2.0f * W[i];
    for (int i = tid; i < 2 * NPHEN; i += 256) sM[i] = M[i];
    __syncthreads();

    const int b = blockIdx.x * 256 + tid;

    float f0 = 0.0f, f1 = 0.0f;

    // ---- numerical features: 16 x float4, per-thread-contiguous row ----
    const float4* nx = reinterpret_cast<const float4*>(num_x + (size_t)b * NNUM);
    #pragma unroll
    for (int i = 0; i < NNUM / 4; ++i) {
        float4 v = nx[i];
        const float* vp = reinterpret_cast<const float*>(&v);
        #pragma unroll
        for (int j = 0; j < 4; ++j) {
            const int k = i * 4 + j;
            float x  = vp[j];
            float t0 = tanh_from_2x(sW2[k] * x);           // sW2 = 2*W
            float t1 = tanh_from_2x(sW2[NFEAT + k] * x);
            f0 = fmaf(sM[k], t0, f0);
            f1 = fmaf(sM[NPHEN + k], t1, f1);
        }
    }

    // ---- categorical features: 32 x (2 x float4), fully coalesced ----
    #pragma unroll 4
    for (int f = 0; f < FCAT; ++f) {
        const float4* cx = reinterpret_cast<const float4*>(
            cat_x + (size_t)f * (size_t)Bn * NCAT + (size_t)b * NCAT);
        float4 v0 = cx[0];
        float4 v1 = cx[1];
        const float* vp0 = reinterpret_cast<const float*>(&v0);
        const float* vp1 = reinterpret_cast<const float*>(&v1);
        const float* w0 = &sW2[NNUM + f * NCAT];           // 2*W_cat[0][f][:]
        const float* w1 = &sW2[NFEAT + NNUM + f * NCAT];   // 2*W_cat[1][f][:]
        float d0 = 0.0f, d1 = 0.0f;                        // accumulate 2*dot
        #pragma unroll
        for (int n = 0; n < 4; ++n) {
            d0 = fmaf(w0[n], vp0[n], d0);
            d1 = fmaf(w1[n], vp0[n], d1);
        }
        #pragma unroll
        for (int n = 0; n < 4; ++n) {
            d0 = fmaf(w0[4 + n], vp1[n], d0);
            d1 = fmaf(w1[4 + n], vp1[n], d1);
        }
        float t0 = tanh_from_2x(d0);
        float t1 = tanh_from_2x(d1);
        f0 = fmaf(sM[NNUM + f], t0, f0);
        f1 = fmaf(sM[NPHEN + NNUM + f], t1, f1);
    }

    // ---- stable 2-class softmax: o0 = 1/(1+exp(f1-f0)) ----
    float e10 = __expf(f1 - f0);
    float o0  = __builtin_amdgcn_rcpf(1.0f + e10);
    out[b]             = o0;
    out[(size_t)Bn + b] = 1.0f - o0;
}

extern "C" void kernel_launch(void* const* d_in, const int* in_sizes, int n_in,
                              void* d_out, int out_size, void* d_ws, size_t ws_size,
                              hipStream_t stream) {
    const float* num_x = (const float*)d_in[0];
    const float* cat_x = (const float*)d_in[1];
    const float* W     = (const float*)d_in[2];
    const float* M     = (const float*)d_in[3];
    float* out = (float*)d_out;

    dim3 grid(Bn / 256), block(256);
    hipLaunchKernelGGL(model_kernel, grid, block, 0, stream,
                       num_x, cat_x, W, M, out);
}